// Round 2
// 443.408 us; speedup vs baseline: 1.0365x; 1.0365x over previous
//
#include <hip/hip_runtime.h>
#include <cstdint>

typedef unsigned short u16;
typedef unsigned int u32;

typedef __attribute__((ext_vector_type(8))) short bf16x8;
typedef __attribute__((ext_vector_type(4))) float f32x4;

// x: (32,128,112,112) f32 ; routing_w: (4,128) ; routing_b: (4,)
// expert_weight: (4,256,128,3,3) ; out: (32,256,56,56) f32
#define KDIM 1152       // 9*128, k = (kh*3+kw)*128 + ci  (tap-major)
#define MDIM 256
#define NPIX 3136
#define PLANE 12544     // 112*112
#define EWSTRIDE 294912 // 256*1152
#define HH 114          // haloed spatial dim
#define XT_SAMP ((size_t)HH * HH * 128)  // u16 per sample

__device__ __forceinline__ u16 f2bf(float f) {
  u32 u = __float_as_uint(f);
  return (u16)((u + 0x7FFFu + ((u >> 16) & 1u)) >> 16);
}

__device__ __forceinline__ void gl_lds16(const u16* g, u16* l) {
  __builtin_amdgcn_global_load_lds((__attribute__((address_space(1))) void*)g,
                                   (__attribute__((address_space(3))) void*)l,
                                   16, 0, 0);
}

// ---- transpose NCHW f32 -> NHWC-halo bf16, fused pool partials + halo zeroing ----
// grid (112 h, 32 b), 256 thr. Block: all 128 ci x 112 w of one (b,h) row.
__global__ __launch_bounds__(256) void transpose_pool_kernel(
    const float* __restrict__ x, u16* __restrict__ xt, float* __restrict__ part) {
  __shared__ u32 tile[112 * 68];   // [w][ci/2], stride 68 words (16B aligned rows)
  __shared__ float psum[512];
  const int h = blockIdx.x, b = blockIdx.y;
  const int t = threadIdx.x, lane = t & 63, wave = t >> 6;

  // fused halo: zero w=0 / w=113 of this block's output row (h+1)
  {
    u32* xrow = (u32*)xt + ((size_t)b * HH + (h + 1)) * HH * 64;
    if (t < 128) {
      const int w = (t >= 64) ? 113 : 0;
      xrow[(size_t)w * 64 + (t & 63)] = 0u;
    }
    // blocks h==0 / h==111 additionally zero full border rows 0 / 113
    if (h == 0 || h == 111) {
      u32* xr = (u32*)xt + ((size_t)b * HH + (h == 0 ? 0 : 113)) * HH * 64;
      for (int i = t; i < HH * 64; i += 256) xr[i] = 0u;
    }
  }

  const float* xb = x + (size_t)b * 128 * PLANE + h * 112;
  if (lane < 56) {
    #pragma unroll
    for (int wh = 0; wh < 2; ++wh) {
      const int w = wh * 56 + lane;
      #pragma unroll
      for (int i = 0; i < 4; ++i) {
        const int ci0 = (i * 4 + wave) * 8;
        const float* p = xb + (size_t)ci0 * PLANE + w;
        float v0 = p[0];
        float v1 = p[(size_t)1 * PLANE];
        float v2 = p[(size_t)2 * PLANE];
        float v3 = p[(size_t)3 * PLANE];
        float v4 = p[(size_t)4 * PLANE];
        float v5 = p[(size_t)5 * PLANE];
        float v6 = p[(size_t)6 * PLANE];
        float v7 = p[(size_t)7 * PLANE];
        uint4 d;
        d.x = (u32)f2bf(v0) | ((u32)f2bf(v1) << 16);
        d.y = (u32)f2bf(v2) | ((u32)f2bf(v3) << 16);
        d.z = (u32)f2bf(v4) | ((u32)f2bf(v5) << 16);
        d.w = (u32)f2bf(v6) | ((u32)f2bf(v7) << 16);
        *(uint4*)&tile[w * 68 + ci0 / 2] = d;
      }
    }
  }
  __syncthreads();
  // write out contiguous 112*64 u32; accumulate fp32 pool sums (thread owns ci pair)
  const int c = t & 63;
  float s0 = 0.f, s1 = 0.f;
  u32* xg = (u32*)xt + (((size_t)b * HH + h + 1) * HH + 1) * 64;
  #pragma unroll
  for (int j = 0; j < 28; ++j) {
    const int idx = t + 256 * j;
    const int w = idx >> 6;
    const u32 v = tile[w * 68 + c];
    s0 += __uint_as_float(v << 16);
    s1 += __uint_as_float(v & 0xffff0000u);
    xg[(size_t)w * 64 + c] = v;
  }
  psum[wave * 128 + 2 * c] = s0;
  psum[wave * 128 + 2 * c + 1] = s1;
  __syncthreads();
  if (t < 128)
    part[((size_t)h * 32 + b) * 128 + t] =
        psum[t] + psum[128 + t] + psum[256 + t] + psum[384 + t];
}

// ---- fused reduce-over-h + routing. grid 32 (b), 256 thr ----
__global__ __launch_bounds__(256) void reduce_routing_kernel(
    const float* __restrict__ part, const float* __restrict__ rww,
    const float* __restrict__ rwb, float* __restrict__ rw) {
  __shared__ float red[256];
  __shared__ float pl[128];
  const int b = blockIdx.x, t = threadIdx.x;
  const int ci = t & 127, half = t >> 7;
  float s = 0.f;
  const float* p = part + ((size_t)(half * 56) * 32 + b) * 128 + ci;
  #pragma unroll 4
  for (int h = 0; h < 56; ++h) s += p[(size_t)h * 32 * 128];
  red[t] = s;
  __syncthreads();
  if (t < 128) pl[t] = red[t] + red[t + 128];
  __syncthreads();
  const int e = t >> 6, l = t & 63;
  float acc = pl[l] * rww[e * 128 + l] + pl[l + 64] * rww[e * 128 + l + 64];
  #pragma unroll
  for (int off = 32; off > 0; off >>= 1) acc += __shfl_down(acc, off, 64);
  if (l == 0) {
    const float logit = acc * (1.0f / (float)PLANE) + rwb[e];
    rw[b * 4 + e] = 1.0f / (1.0f + expf(-logit));
  }
}

// ---- mix: Wmix[b][oc][(kh*3+kw)*128+ci] = sum_e rw[b,e]*ew[e][oc][ci][kh,kw]
// grid (64 ocgrp, 8 bgrp): 512 blocks -> 2/CU for latency hiding
__global__ __launch_bounds__(256) void mix_kernel(const float* __restrict__ ew,
                                                  const float* __restrict__ rw,
                                                  u16* __restrict__ wmix) {
  const int t = threadIdx.x;
  const int oc = blockIdx.x * 4 + (t >> 6);
  const int lane = t & 63;
  const int b0 = blockIdx.y * 4;
  float ereg[4][18];
  #pragma unroll
  for (int e = 0; e < 4; ++e) {
    const float* p = ew + ((size_t)e * 256 + oc) * 1152 + lane * 18;
    #pragma unroll
    for (int j = 0; j < 18; ++j) ereg[e][j] = p[j];
  }
  for (int bb = 0; bb < 4; ++bb) {
    const int b = b0 + bb;
    const float w0 = rw[b * 4 + 0], w1 = rw[b * 4 + 1];
    const float w2 = rw[b * 4 + 2], w3 = rw[b * 4 + 3];
    u32* dst = (u32*)(wmix + ((size_t)b * 256 + oc) * KDIM) + lane;
    #pragma unroll
    for (int r = 0; r < 9; ++r) {
      const float va = w0 * ereg[0][r] + w1 * ereg[1][r] + w2 * ereg[2][r] + w3 * ereg[3][r];
      const float vb = w0 * ereg[0][9 + r] + w1 * ereg[1][9 + r] + w2 * ereg[2][9 + r] + w3 * ereg[3][9 + r];
      dst[r * 64] = (u32)f2bf(va) | ((u32)f2bf(vb) << 16);
    }
  }
}

// ---- GEMM with implicit im2col. grid (32 b, 50 tiles): id ≡ b (mod 8) -> XCD locality
// Two 32-wide K-chunks staged into disjoint LDS buffers per barrier pair:
// 32 MFMA between vmcnt(0)-drains instead of 16 (halves barrier-drain count).
__global__ __launch_bounds__(256) void gemm_kernel(const u16* __restrict__ wmix,
                                                   const u16* __restrict__ xt,
                                                   float* __restrict__ out) {
  __shared__ u16 a_sm[2][128 * 32];
  __shared__ u16 b_sm[2][128 * 32];
  const int b = blockIdx.x;
  const int mt = blockIdx.y & 1, nt = blockIdx.y >> 1;
  const int tid = threadIdx.x, lane = tid & 63, wave = tid >> 6;
  const int srow = lane >> 2, scol = (lane & 3) * 8;
  const u16* ga0 = wmix + (size_t)b * EWSTRIDE + (size_t)(mt * 128 + wave * 16 + srow) * KDIM + scol;
  const u16* ga1 = ga0 + 64 * KDIM;
  const u16* xtb = xt + (size_t)b * XT_SAMP;
  int p0 = nt * 128 + wave * 16 + (lane >> 2);
  int p1 = p0 + 64;
  if (p0 > NPIX - 1) p0 = NPIX - 1;
  if (p1 > NPIX - 1) p1 = NPIX - 1;
  const size_t pb0 = ((size_t)(2 * (p0 / 56)) * HH + 2 * (p0 % 56)) * 128 + scol;
  const size_t pb1 = ((size_t)(2 * (p1 / 56)) * HH + 2 * (p1 % 56)) * 128 + scol;

  u16* la00 = &a_sm[0][wave * 512 + lane * 8];
  u16* la01 = la00 + 2048;
  u16* la10 = &a_sm[1][wave * 512 + lane * 8];
  u16* la11 = la10 + 2048;
  u16* lb00 = &b_sm[0][wave * 512 + lane * 8];
  u16* lb01 = lb00 + 2048;
  u16* lb10 = &b_sm[1][wave * 512 + lane * 8];
  u16* lb11 = lb10 + 2048;

  const int wm = wave >> 1, wn = wave & 1;
  const int fr = lane & 15, quad = lane >> 4;
  f32x4 acc[4][4];
  const f32x4 zv = {0.f, 0.f, 0.f, 0.f};
  #pragma unroll
  for (int i = 0; i < 4; ++i)
    #pragma unroll
    for (int j = 0; j < 4; ++j) acc[i][j] = zv;

  for (int kt2 = 0; kt2 < 18; ++kt2) {
    const int k0 = kt2 * 2;
    const int r = k0 >> 2;
    const size_t tap = (size_t)((r / 3) * HH + (r % 3)) * 128;
    const size_t t0 = tap + (size_t)(k0 & 3) * 32;
    const size_t t1 = t0 + 32;
    // stage chunk k0 -> buffer 0, chunk k0+1 -> buffer 1
    gl_lds16(ga0 + k0 * 32, la00);
    gl_lds16(ga1 + k0 * 32, la01);
    gl_lds16(xtb + pb0 + t0, lb00);
    gl_lds16(xtb + pb1 + t0, lb01);
    gl_lds16(ga0 + k0 * 32 + 32, la10);
    gl_lds16(ga1 + k0 * 32 + 32, la11);
    gl_lds16(xtb + pb0 + t1, lb10);
    gl_lds16(xtb + pb1 + t1, lb11);
    __syncthreads();
    #pragma unroll
    for (int c = 0; c < 2; ++c) {
      const u16* as = a_sm[c];
      const u16* bs = b_sm[c];
      bf16x8 av[4], bv[4];
      #pragma unroll
      for (int i = 0; i < 4; ++i)
        av[i] = *(const bf16x8*)(as + (wm * 64 + i * 16 + fr) * 32 + quad * 8);
      #pragma unroll
      for (int j = 0; j < 4; ++j)
        bv[j] = *(const bf16x8*)(bs + (wn * 64 + j * 16 + fr) * 32 + quad * 8);
      #pragma unroll
      for (int i = 0; i < 4; ++i)
        #pragma unroll
        for (int j = 0; j < 4; ++j)
          acc[i][j] = __builtin_amdgcn_mfma_f32_16x16x32_bf16(av[i], bv[j], acc[i][j], 0, 0, 0);
    }
    __syncthreads();
  }

  float* os = out + (size_t)b * MDIM * NPIX;
  const int mbase = mt * 128 + wm * 64 + quad * 4;
  const int nb = nt * 128 + wn * 64 + fr;
  #pragma unroll
  for (int j = 0; j < 4; ++j) {
    const int n = nb + j * 16;
    if (n < NPIX) {
      #pragma unroll
      for (int i = 0; i < 4; ++i) {
        const int m = mbase + i * 16;
        #pragma unroll
        for (int rr = 0; rr < 4; ++rr)
          os[(size_t)(m + rr) * NPIX + n] = acc[i][j][rr];
      }
    }
  }
}

// ---- fallback path (ws too small): pool + naive direct conv ----
__global__ void routing_kernel(const float* __restrict__ pooled,
                               const float* __restrict__ rww,
                               const float* __restrict__ rwb,
                               float* __restrict__ rw, float scale) {
  const int t = threadIdx.x;
  if (t >= 128) return;
  const int b = t >> 2, e = t & 3;
  float acc = rwb[e];
  for (int c = 0; c < 128; ++c) acc += pooled[b * 128 + c] * scale * rww[e * 128 + c];
  rw[b * 4 + e] = 1.0f / (1.0f + expf(-acc));
}

__global__ __launch_bounds__(256) void pool_kernel(const float* __restrict__ x,
                                                   float* __restrict__ pooled) {
  const int ci = blockIdx.x, b = blockIdx.y;
  const float4* p = (const float4*)(x + ((size_t)b * 128 + ci) * PLANE);
  float s = 0.f;
  for (int i = threadIdx.x; i < PLANE / 4; i += 256) {
    float4 v = p[i];
    s += v.x + v.y + v.z + v.w;
  }
  #pragma unroll
  for (int off = 32; off > 0; off >>= 1) s += __shfl_down(s, off, 64);
  __shared__ float red[4];
  if ((threadIdx.x & 63) == 0) red[threadIdx.x >> 6] = s;
  __syncthreads();
  if (threadIdx.x == 0)
    pooled[b * 128 + ci] = (red[0] + red[1] + red[2] + red[3]) * (1.0f / (float)PLANE);
}

__global__ __launch_bounds__(256) void naive_conv(const float* __restrict__ x,
                                                  const float* __restrict__ ew,
                                                  const float* __restrict__ rw,
                                                  float* __restrict__ out) {
  const size_t idx = (size_t)blockIdx.x * 256 + threadIdx.x;
  if (idx >= (size_t)32 * MDIM * NPIX) return;
  const int n = (int)(idx % NPIX);
  const int tmp = (int)(idx / NPIX);
  const int oc = tmp % MDIM;
  const int b = tmp / MDIM;
  const int oh = n / 56, ow = n % 56;
  const float w0 = rw[b * 4 + 0], w1 = rw[b * 4 + 1];
  const float w2 = rw[b * 4 + 2], w3 = rw[b * 4 + 3];
  float acc = 0.f;
  for (int ci = 0; ci < 128; ++ci) {
    const float* xp = x + ((size_t)b * 128 + ci) * PLANE;
    const size_t wb = ((size_t)oc * 128 + ci) * 9;
    for (int kh = 0; kh < 3; ++kh) {
      const int ih = 2 * oh - 1 + kh;
      if (ih < 0 || ih >= 112) continue;
      for (int kw = 0; kw < 3; ++kw) {
        const int iw = 2 * ow - 1 + kw;
        if (iw < 0 || iw >= 112) continue;
        const int ko = kh * 3 + kw;
        const float wsum = w0 * ew[wb + ko] + w1 * ew[(size_t)EWSTRIDE + wb + ko]
                         + w2 * ew[2 * (size_t)EWSTRIDE + wb + ko]
                         + w3 * ew[3 * (size_t)EWSTRIDE + wb + ko];
        acc += xp[ih * 112 + iw] * wsum;
      }
    }
  }
  out[idx] = acc;
}

extern "C" void kernel_launch(void* const* d_in, const int* in_sizes, int n_in,
                              void* d_out, int out_size, void* d_ws, size_t ws_size,
                              hipStream_t stream) {
  const float* x   = (const float*)d_in[0];
  const float* rww = (const float*)d_in[1];
  const float* rwb = (const float*)d_in[2];
  const float* ew  = (const float*)d_in[3];
  float* out = (float*)d_out;

  const size_t xt_bytes = 32 * XT_SAMP * 2;                     // 106,463,232
  const size_t wmix_off = xt_bytes;
  const size_t part_off = wmix_off + (size_t)32 * EWSTRIDE * 2; // +18,874,368
  const size_t pooled_off = part_off + (size_t)112 * 32 * 128 * 4;  // +1,835,008
  const size_t rw_off = pooled_off + 16384;
  const size_t need = rw_off + 512;

  if (ws_size >= need) {
    u16* xt = (u16*)d_ws;
    u16* wmix = (u16*)((char*)d_ws + wmix_off);
    float* part = (float*)((char*)d_ws + part_off);
    float* rw_ws = (float*)((char*)d_ws + rw_off);
    transpose_pool_kernel<<<dim3(112, 32), 256, 0, stream>>>(x, xt, part);
    reduce_routing_kernel<<<32, 256, 0, stream>>>(part, rww, rwb, rw_ws);
    mix_kernel<<<dim3(64, 8), 256, 0, stream>>>(ew, rw_ws, wmix);
    gemm_kernel<<<dim3(32, 50), 256, 0, stream>>>(wmix, xt, out);
  } else {
    float* pooled = (float*)d_ws;
    float* rw_ws = (float*)((char*)d_ws + 16384);
    pool_kernel<<<dim3(128, 32), 256, 0, stream>>>(x, pooled);
    routing_kernel<<<1, 128, 0, stream>>>(pooled, rww, rwb, rw_ws, 1.0f);
    naive_conv<<<(int)(((size_t)32 * MDIM * NPIX + 255) / 256), 256, 0, stream>>>(
        x, ew, rw_ws, out);
  }
}